// Round 8
// baseline (1849.817 us; speedup 1.0000x reference)
//
#include <hip/hip_runtime.h>
#include <math.h>

#define N_UE 16384
#define N_AP 128
#define NE   2097152
#define NSB  256               // sort blocks
#define EPSB (NE / NSB)        // 8192 edges per sort block
#define EBLK 1024              // edge_layer blocks (= NPART)
#define NPART EBLK
#define NPW  4                 // nodes per wave

__device__ __forceinline__ float frl(float x, int l) {
    return __int_as_float(__builtin_amdgcn_readlane(__float_as_int(x), l));
}

// ---------------------------------------------------------------------------
// init: Qua1[u][d] = x_ue[u]*Wm1_ua[0][d] + bm1_ua[d];  Pau1[a][d] = bm1_au[d]
// ---------------------------------------------------------------------------
__global__ __launch_bounds__(256) void init_kernel(
    const float* __restrict__ x_ue, const float* __restrict__ Wm1_ua,
    const float* __restrict__ bm1_ua, const float* __restrict__ bm1_au,
    float* __restrict__ Qua, float* __restrict__ Pau)
{
    int i = blockIdx.x * 256 + threadIdx.x;
    int d = i & 31;
    Qua[i] = fmaf(x_ue[i >> 5], Wm1_ua[d], bm1_ua[d]);
    if (i < N_AP * 32) Pau[i] = bm1_au[d];
}

// ---------------------------------------------------------------------------
// src-sort: histogram -> column scan -> prefix scan -> scatter
// ---------------------------------------------------------------------------
__global__ __launch_bounds__(256) void hist_src(
    const int* __restrict__ src, int* __restrict__ histS)
{
    __shared__ int h[N_UE];
    for (int i = threadIdx.x; i < N_UE; i += 256) h[i] = 0;
    __syncthreads();
    const int beg = blockIdx.x * EPSB;
    for (int e = beg + threadIdx.x; e < beg + EPSB; e += 256)
        atomicAdd(&h[src[e]], 1);
    __syncthreads();
    for (int i = threadIdx.x; i < N_UE; i += 256) histS[blockIdx.x * N_UE + i] = h[i];
}

__global__ __launch_bounds__(256) void colscan_kernel(
    const int* __restrict__ histS, int* __restrict__ baseS, int* __restrict__ cnt)
{
    const int u = blockIdx.x * 256 + threadIdx.x;
    int run = 0;
    for (int b = 0; b < NSB; ++b) {
        int t = histS[b * N_UE + u];
        baseS[b * N_UE + u] = run;
        run += t;
    }
    cnt[u] = run;
}

__global__ __launch_bounds__(256) void scan_kernel(
    const int* __restrict__ cnt, int* __restrict__ offs)
{
    __shared__ int ps[256];
    __shared__ int ps2[257];
    const int t = threadIdx.x;
    const int b0 = t * (N_UE / 256);
    int s = 0;
    for (int i = 0; i < N_UE / 256; ++i) s += cnt[b0 + i];
    ps[t] = s;
    __syncthreads();
    if (t == 0) {
        int r = 0;
        for (int i = 0; i < 256; ++i) { ps2[i] = r; r += ps[i]; }
        ps2[256] = r;
    }
    __syncthreads();
    int r = ps2[t];
    for (int i = 0; i < N_UE / 256; ++i) { offs[b0 + i] = r; r += cnt[b0 + i]; }
    if (t == 255) offs[N_UE] = ps2[256];
}

__global__ __launch_bounds__(256) void scatter_src(
    const int* __restrict__ src, const int* __restrict__ dst,
    const float2* __restrict__ e0ua, const float2* __restrict__ e0au,
    const int* __restrict__ baseS, const int* __restrict__ offs,
    int* __restrict__ dtS, float4* __restrict__ att0, int* __restrict__ invS)
{
    __shared__ int cursor[N_UE];
    const int b = blockIdx.x;
    for (int i = threadIdx.x; i < N_UE; i += 256)
        cursor[i] = offs[i] + baseS[b * N_UE + i];
    __syncthreads();
    const int beg = b * EPSB;
    for (int e = beg + threadIdx.x; e < beg + EPSB; e += 256) {
        int s = src[e];
        int pos = atomicAdd(&cursor[s], 1);
        dtS[pos] = dst[e];
        float2 a = e0ua[e], c = e0au[e];
        att0[pos] = make_float4(a.x, a.y, c.x, c.y);
        invS[e] = pos;
    }
}

// ---------------------------------------------------------------------------
// Fused edge layer. One wave64 per NPW consecutive UE nodes (src-CSR).
// Per 64-edge batch:
//   lane=edge: coalesced dt/att load; fused edge updates (gathers RapA/B[dt],
//              L1-hot 1KB); coalesced attOut store.
//   j-loop (unrolled 32, 2 edges/iter via halves): readlane broadcast (VALU),
//              Pau[dt] row gather (L1-hot 16KB, independent iters),
//              m_au -> register acc (exclusive agg_ue row store),
//              m_ua -> single exec-masked ds_add (bank-clean, fire-forget).
// No other DS ops, no global atomics, no dependent load chains.
// ---------------------------------------------------------------------------
template<bool EUPD>
__global__ __launch_bounds__(256) void edge_layer(
    const int* __restrict__ offs, const int* __restrict__ dtS,
    const float4* __restrict__ attIn, float4* __restrict__ attOut,
    const float2* __restrict__ RueA, const float2* __restrict__ RueB,
    const float2* __restrict__ RapA, const float2* __restrict__ RapB,
    const float* __restrict__ EcA, const float* __restrict__ EcB,
    const float* __restrict__ Qua, const float* __restrict__ Pau,
    const float* __restrict__ cu, const float* __restrict__ cw,
    float* __restrict__ agg_ue, float* __restrict__ partial_ap)
{
    __shared__ float aggap_s[N_AP * 32];   // 16 KB
    const int tid  = threadIdx.x;
    const int wv   = tid >> 6;
    const int lane = tid & 63;
    const int dim  = lane & 31;
    const int h32  = lane & 32;            // 0 or 32

    for (int i = tid; i < N_AP * 32; i += 256) aggap_s[i] = 0.f;
    __syncthreads();

    const float u0 = cu[dim], u1 = cu[32 + dim];
    const float w0 = cw[dim], w1 = cw[32 + dim];
    float c00 = 0.f, c01 = 0.f, c10 = 0.f, c11 = 0.f;
    float d00 = 0.f, d01 = 0.f, d10 = 0.f, d11 = 0.f;
    if constexpr (EUPD) {
        c00 = EcA[0]; c01 = EcA[1]; c10 = EcA[2]; c11 = EcA[3];
        d00 = EcB[0]; d01 = EcB[1]; d10 = EcB[2]; d11 = EcB[3];
    }

    const int w = blockIdx.x * 4 + wv;
    for (int n = 0; n < NPW; ++n) {
        const int u = w * NPW + n;
        const int e0 = offs[u], e1 = offs[u + 1];
        const float qrow = Qua[u * 32 + dim];       // wave-uniform row
        float ruAx = 0.f, ruAy = 0.f, ruBx = 0.f, ruBy = 0.f;
        if constexpr (EUPD) {
            float2 rA = RueA[u]; ruAx = rA.x; ruAy = rA.y;
            float2 rB = RueB[u]; ruBx = rB.x; ruBy = rB.y;
        }
        float acc = 0.f;
        for (int ebase = e0; ebase < e1; ebase += 64) {
            const int rem  = e1 - ebase;
            const int idx  = ebase + lane;
            const int idxc = idx < NE ? idx : NE - 1;
            int    dt = dtS[idxc];                  // coalesced bulk load
            float4 a4 = attIn[idxc];                // coalesced bulk load
            if constexpr (EUPD) {
                float2 pA = RapA[dt], pB = RapB[dt];     // L1-hot 1KB gathers
                float n0 = fmaxf(ruAx + pA.x + a4.x * c00 + a4.y * c10, 0.f);
                float n1 = fmaxf(ruAy + pA.y + a4.x * c01 + a4.y * c11, 0.f);
                float m0 = fmaxf(ruBx + pB.x + a4.z * d00 + a4.w * d10, 0.f);
                float m1 = fmaxf(ruBy + pB.y + a4.z * d01 + a4.w * d11, 0.f);
                a4 = make_float4(n0, n1, m0, m1);
                if (lane < rem) attOut[idx] = a4;   // coalesced store
            }
            #pragma unroll
            for (int j = 0; j < 32; ++j) {
                int   dtl = __builtin_amdgcn_readlane(dt, j);
                int   dth = __builtin_amdgcn_readlane(dt, j + 32);
                int   dtj = h32 ? dth : dtl;
                float ax  = h32 ? frl(a4.x, j + 32) : frl(a4.x, j);
                float ay  = h32 ? frl(a4.y, j + 32) : frl(a4.y, j);
                float az  = h32 ? frl(a4.z, j + 32) : frl(a4.z, j);
                float aw  = h32 ? frl(a4.w, j + 32) : frl(a4.w, j);
                float p   = Pau[dtj * 32 + dim];    // L1-hot, independent
                float mau = fmaxf(fmaf(az, w0, fmaf(aw, w1, p)), 0.f);
                float mua = fmaxf(fmaf(ax, u0, fmaf(ay, u1, qrow)), 0.f);
                bool  v   = (j + h32) < rem;
                acc += v ? mau : 0.f;
                if (v) atomicAdd(&aggap_s[dtj * 32 + dim], mua);  // only DS op
            }
        }
        acc += __shfl_xor(acc, 32);                 // combine halves
        if (h32 == 0) agg_ue[u * 32 + dim] = acc;   // exclusive owner store
    }

    __syncthreads();
    float* outp = partial_ap + (size_t)blockIdx.x * (N_AP * 32);
    for (int i = tid; i < N_AP * 32; i += 256) outp[i] = aggap_s[i];
}

// ---------------------------------------------------------------------------
// Final layer-4 edge update, original order (gather via invS).
// ---------------------------------------------------------------------------
__global__ __launch_bounds__(256) void final_edge(
    const int* __restrict__ src, const int* __restrict__ dst,
    const int* __restrict__ invS, const float4* __restrict__ att,
    const float2* __restrict__ RueA, const float2* __restrict__ RueB,
    const float2* __restrict__ RapA, const float2* __restrict__ RapB,
    const float* __restrict__ EcA, const float* __restrict__ EcB,
    float2* __restrict__ out_eua, float2* __restrict__ out_eau)
{
    const int e = blockIdx.x * 256 + threadIdx.x;
    const int s = src[e], dt = dst[e];
    float4 a4 = att[invS[e]];
    float c00 = EcA[0], c01 = EcA[1], c10 = EcA[2], c11 = EcA[3];
    float d00 = EcB[0], d01 = EcB[1], d10 = EcB[2], d11 = EcB[3];
    float2 rA = RueA[s], pA = RapA[dt];
    float n0 = fmaxf(rA.x + pA.x + a4.x * c00 + a4.y * c10, 0.f);
    float n1 = fmaxf(rA.y + pA.y + a4.x * c01 + a4.y * c11, 0.f);
    float2 rB = RueB[s], pB = RapB[dt];
    float m0 = fmaxf(rB.x + pB.x + a4.z * d00 + a4.w * d10, 0.f);
    float m1 = fmaxf(rB.y + pB.y + a4.z * d01 + a4.w * d11, 0.f);
    out_eua[e] = make_float2(n0, n1);
    out_eau[e] = make_float2(m0, m1);
}

// ---------------------------------------------------------------------------
// UE node update + next-layer tables (+ power head for LAST)
// ---------------------------------------------------------------------------
template<bool FIRST, bool LAST>
__global__ __launch_bounds__(256) void node_ue_kernel(
    const float* __restrict__ x_prev, const float* __restrict__ agg_ue,
    const float* __restrict__ Wu, const float* __restrict__ bu,
    const float* __restrict__ Wm_next, const float* __restrict__ bm_next,
    const float* __restrict__ WeUa, const float* __restrict__ WeUb,
    const float* __restrict__ Wp1, const float* __restrict__ bp1,
    const float* __restrict__ Wp2, const float* __restrict__ bp2,
    float* __restrict__ x_new, float* __restrict__ Qua_next,
    float2* __restrict__ RueA, float2* __restrict__ RueB,
    float2* __restrict__ ue_out)
{
    constexpr int KIN = FIRST ? 33 : 64;
    __shared__ float Wu_s[64 * 32];
    __shared__ float Wm_s[32 * 32];
    __shared__ float WeA_s[64], WeB_s[64];
    __shared__ float bu_s[32], bm_s[32];
    __shared__ float Wp1_s[32 * 16], bp1_s[16], Wp2_s[16];

    const int tid = threadIdx.x;
    for (int i = tid; i < KIN * 32; i += 256) Wu_s[i] = Wu[i];
    if (tid < 32) bu_s[tid] = bu[tid];
    if (!LAST) {
        for (int i = tid; i < 1024; i += 256) Wm_s[i] = Wm_next[i];
        if (tid < 32) bm_s[tid] = bm_next[tid];
    }
    if (tid < 64) { WeA_s[tid] = WeUa[tid]; WeB_s[tid] = WeUb[tid]; }
    if (LAST) {
        for (int i = tid; i < 512; i += 256) Wp1_s[i] = Wp1[i];
        if (tid < 16) { bp1_s[tid] = bp1[tid]; Wp2_s[tid] = Wp2[tid]; }
    }
    __syncthreads();

    const int u = blockIdx.x * 256 + tid;
    float in[KIN];
    if (FIRST) {
        in[0] = x_prev[u];
        #pragma unroll
        for (int k = 0; k < 32; ++k) in[1 + k] = agg_ue[u * 32 + k];
    } else {
        #pragma unroll
        for (int k = 0; k < 32; ++k) in[k] = x_prev[u * 32 + k];
        #pragma unroll
        for (int k = 0; k < 32; ++k) in[32 + k] = agg_ue[u * 32 + k];
    }
    float out[32];
    #pragma unroll
    for (int d = 0; d < 32; ++d) {
        float acc = bu_s[d];
        #pragma unroll
        for (int k = 0; k < KIN; ++k) acc = fmaf(in[k], Wu_s[k * 32 + d], acc);
        out[d] = fmaxf(acc, 0.f);
    }
    #pragma unroll
    for (int d = 0; d < 32; ++d) x_new[u * 32 + d] = out[d];
    if (!LAST) {
        #pragma unroll
        for (int d = 0; d < 32; ++d) {
            float acc = bm_s[d];
            #pragma unroll
            for (int k = 0; k < 32; ++k) acc = fmaf(out[k], Wm_s[k * 32 + d], acc);
            Qua_next[u * 32 + d] = acc;
        }
    }
    float r0 = 0.f, r1 = 0.f, s0 = 0.f, s1 = 0.f;
    #pragma unroll
    for (int k = 0; k < 32; ++k) {
        r0 = fmaf(out[k], WeA_s[k * 2],     r0);
        r1 = fmaf(out[k], WeA_s[k * 2 + 1], r1);
        s0 = fmaf(out[k], WeB_s[k * 2],     s0);
        s1 = fmaf(out[k], WeB_s[k * 2 + 1], s1);
    }
    RueA[u] = make_float2(r0, r1);
    RueB[u] = make_float2(s0, s1);
    if (LAST) {
        float z = bp2[0];
        #pragma unroll
        for (int j = 0; j < 16; ++j) {
            float h = bp1_s[j];
            #pragma unroll
            for (int k = 0; k < 32; ++k) h = fmaf(out[k], Wp1_s[k * 16 + j], h);
            z = fmaf(fmaxf(h, 0.f), Wp2_s[j], z);
        }
        float pw = 1.f / (1.f + expf(-z));
        ue_out[u] = make_float2(out[0], pw);
    }
}

// ---------------------------------------------------------------------------
// AP: reduce partials -> agg_ap, node update, next-layer tables
// ---------------------------------------------------------------------------
template<bool FIRST, bool LAST>
__global__ __launch_bounds__(256) void node_ap_kernel(
    const float* __restrict__ partial,
    const float* __restrict__ x_prev,
    const float* __restrict__ Wu, const float* __restrict__ bu,
    const float* __restrict__ Wm_next, const float* __restrict__ bm_next,
    const float* __restrict__ WeA, const float* __restrict__ beA,
    const float* __restrict__ WeB, const float* __restrict__ beB,
    float* __restrict__ x_new, float* __restrict__ Pau_next,
    float2* __restrict__ RapA, float2* __restrict__ RapB)
{
    __shared__ float red[256];
    __shared__ float agg_s[32];
    __shared__ float xnew_s[32];
    const int a = blockIdx.x, tid = threadIdx.x;
    const int d = tid & 31, p0 = tid >> 5;
    float acc = 0.f;
    for (int p = p0; p < NPART; p += 8)
        acc += partial[(size_t)p * (N_AP * 32) + a * 32 + d];
    red[tid] = acc;
    __syncthreads();
    if (tid < 32) {
        float s = 0.f;
        #pragma unroll
        for (int i = 0; i < 8; ++i) s += red[i * 32 + tid];
        agg_s[tid] = s;
    }
    __syncthreads();
    if (tid < 32) {
        float acc2 = bu[d];
        if (FIRST) {
            #pragma unroll
            for (int k = 0; k < 32; ++k) acc2 = fmaf(agg_s[k], Wu[k * 32 + d], acc2);
        } else {
            #pragma unroll
            for (int k = 0; k < 32; ++k) acc2 = fmaf(x_prev[a * 32 + k], Wu[k * 32 + d], acc2);
            #pragma unroll
            for (int k = 0; k < 32; ++k) acc2 = fmaf(agg_s[k], Wu[(32 + k) * 32 + d], acc2);
        }
        float xn = fmaxf(acc2, 0.f);
        xnew_s[d] = xn;
        x_new[a * 32 + d] = xn;
    }
    __syncthreads();
    if (!LAST) {
        if (tid < 32) {
            float acc3 = bm_next[d];
            #pragma unroll
            for (int k = 0; k < 32; ++k) acc3 = fmaf(xnew_s[k], Wm_next[k * 32 + d], acc3);
            Pau_next[a * 32 + d] = acc3;
        }
    }
    if (tid == 0) {
        float q0 = beA[0], q1 = beA[1], t0 = beB[0], t1 = beB[1];
        #pragma unroll
        for (int k = 0; k < 32; ++k) {
            q0 = fmaf(xnew_s[k], WeA[k * 2],     q0);
            q1 = fmaf(xnew_s[k], WeA[k * 2 + 1], q1);
            t0 = fmaf(xnew_s[k], WeB[k * 2],     t0);
            t1 = fmaf(xnew_s[k], WeB[k * 2 + 1], t1);
        }
        RapA[a] = make_float2(q0, q1);
        RapB[a] = make_float2(t0, t1);
    }
}

// ---------------------------------------------------------------------------
extern "C" void kernel_launch(void* const* d_in, const int* in_sizes, int n_in,
                              void* d_out_v, int out_size, void* d_ws, size_t ws_size,
                              hipStream_t stream)
{
    const float*  x_ue   = (const float*)d_in[0];
    const float2* e0ua   = (const float2*)d_in[1];
    const float2* e0au   = (const float2*)d_in[2];
    const int*    src    = (const int*)d_in[3];
    const int*    dst    = (const int*)d_in[4];
    const float* Wm1_ua = (const float*)d_in[5];
    const float* bm1_ua = (const float*)d_in[6];
    const float* Wm1_au = (const float*)d_in[7];
    const float* bm1_au = (const float*)d_in[8];
    const float* Wu1_ap = (const float*)d_in[9];
    const float* bu1_ap = (const float*)d_in[10];
    const float* Wu1_ue = (const float*)d_in[11];
    const float* bu1_ue = (const float*)d_in[12];
    const float* We1_ua = (const float*)d_in[13];
    const float* be1_ua = (const float*)d_in[14];
    const float* We1_au = (const float*)d_in[15];
    const float* be1_au = (const float*)d_in[16];
    const float* Wm_ua  = (const float*)d_in[17];
    const float* bm_ua  = (const float*)d_in[18];
    const float* Wm_au  = (const float*)d_in[19];
    const float* bm_au  = (const float*)d_in[20];
    const float* Wu_ap  = (const float*)d_in[21];
    const float* bu_ap  = (const float*)d_in[22];
    const float* Wu_ue  = (const float*)d_in[23];
    const float* bu_ue  = (const float*)d_in[24];
    const float* We_ua  = (const float*)d_in[25];
    const float* be_ua  = (const float*)d_in[26];
    const float* We_au  = (const float*)d_in[27];
    const float* be_au  = (const float*)d_in[28];
    const float* Wp1    = (const float*)d_in[29];
    const float* bp1    = (const float*)d_in[30];
    const float* Wp2    = (const float*)d_in[31];
    const float* bp2    = (const float*)d_in[32];

    float*  outp    = (float*)d_out_v;
    float2* out_ue  = (float2*)outp;                              // [16384][2]
    float*  out_ap  = outp + N_UE * 2;                            // [128][32]
    float2* out_eua = (float2*)(outp + N_UE * 2 + N_AP * 32);     // [E][2]
    float2* out_eau = (float2*)(outp + N_UE * 2 + N_AP * 32 + (size_t)NE * 2);

    float* ws = (float*)d_ws;
    float* x_ueA  = ws;          ws += N_UE * 32;
    float* x_ueB  = ws;          ws += N_UE * 32;
    float* x_apA  = ws;          ws += N_AP * 32;
    float* x_apB  = ws;          ws += N_AP * 32;
    float* agg_ue = ws;          ws += N_UE * 32;
    float* Qua    = ws;          ws += N_UE * 32;
    float* Pau    = ws;          ws += N_AP * 32;
    float2* RueA  = (float2*)ws; ws += N_UE * 2;
    float2* RueB  = (float2*)ws; ws += N_UE * 2;
    float2* RapA  = (float2*)ws; ws += N_AP * 2;
    float2* RapB  = (float2*)ws; ws += N_AP * 2;
    float* partial = ws;         ws += (size_t)NPART * N_AP * 32; // 16 MB
    int* cnt   = (int*)ws;       ws += N_UE;
    int* offs  = (int*)ws;       ws += N_UE + 4;
    int* invS  = (int*)ws;       ws += NE;                        // 8 MB
    int* dtS   = (int*)ws;       ws += NE;                        // 8 MB
    float4* att0 = (float4*)ws;  ws += (size_t)NE * 4;            // 32 MB
    float4* att1 = (float4*)ws;  ws += (size_t)NE * 4;            // 32 MB
    int* histS = (int*)att0;     // alias 16 MB: consumed (colscan) before att0 written
    int* baseS = (int*)att1;     // alias 16 MB: consumed (scatter) before att1 written

    dim3 blk(256);

    // ---- src-sort ----
    hist_src<<<NSB, blk, 0, stream>>>(src, histS);
    colscan_kernel<<<N_UE / 256, blk, 0, stream>>>(histS, baseS, cnt);
    scan_kernel<<<1, blk, 0, stream>>>(cnt, offs);
    scatter_src<<<NSB, blk, 0, stream>>>(src, dst, e0ua, e0au, baseS, offs,
                                         dtS, att0, invS);

    init_kernel<<<N_UE * 32 / 256, blk, 0, stream>>>(x_ue, Wm1_ua, bm1_ua, bm1_au, Qua, Pau);

    // ---- layer 1 ----
    edge_layer<false><<<EBLK, blk, 0, stream>>>(
        offs, dtS, att0, att1, nullptr, nullptr, nullptr, nullptr,
        nullptr, nullptr, Qua, Pau, Wm1_ua + 32, Wm1_au, agg_ue, partial);
    node_ue_kernel<true, false><<<N_UE / 256, blk, 0, stream>>>(
        x_ue, agg_ue, Wu1_ue, bu1_ue, Wm_ua, bm_ua, We1_ua, We1_au,
        nullptr, nullptr, nullptr, nullptr,
        x_ueA, Qua, RueA, RueB, nullptr);
    node_ap_kernel<true, false><<<N_AP, blk, 0, stream>>>(
        partial, nullptr, Wu1_ap, bu1_ap, Wm_au, bm_au,
        We1_ua + 64, be1_ua, We1_au + 64, be1_au,
        x_apA, Pau, RapA, RapB);

    // ---- layer 2 (edge-update 1 fused) ----
    edge_layer<true><<<EBLK, blk, 0, stream>>>(
        offs, dtS, att0, att1, RueA, RueB, RapA, RapB,
        We1_ua + 128, We1_au + 128, Qua, Pau, Wm_ua + 1024, Wm_au + 1024,
        agg_ue, partial);
    node_ue_kernel<false, false><<<N_UE / 256, blk, 0, stream>>>(
        x_ueA, agg_ue, Wu_ue, bu_ue, Wm_ua + 1088, bm_ua + 32, We_ua, We_au,
        nullptr, nullptr, nullptr, nullptr,
        x_ueB, Qua, RueA, RueB, nullptr);
    node_ap_kernel<false, false><<<N_AP, blk, 0, stream>>>(
        partial, x_apA, Wu_ap, bu_ap, Wm_au + 1088, bm_au + 32,
        We_ua + 64, be_ua, We_au + 64, be_au,
        x_apB, Pau, RapA, RapB);

    // ---- layer 3 (edge-update 2 fused) ----
    edge_layer<true><<<EBLK, blk, 0, stream>>>(
        offs, dtS, att1, att0, RueA, RueB, RapA, RapB,
        We_ua + 128, We_au + 128, Qua, Pau, Wm_ua + 2112, Wm_au + 2112,
        agg_ue, partial);
    node_ue_kernel<false, false><<<N_UE / 256, blk, 0, stream>>>(
        x_ueB, agg_ue, Wu_ue + 2048, bu_ue + 32, Wm_ua + 2176, bm_ua + 64,
        We_ua + 132, We_au + 132,
        nullptr, nullptr, nullptr, nullptr,
        x_ueA, Qua, RueA, RueB, nullptr);
    node_ap_kernel<false, false><<<N_AP, blk, 0, stream>>>(
        partial, x_apB, Wu_ap + 2048, bu_ap + 32, Wm_au + 2176, bm_au + 64,
        We_ua + 196, be_ua + 2, We_au + 196, be_au + 2,
        x_apA, Pau, RapA, RapB);

    // ---- layer 4 (edge-update 3 fused) ----
    edge_layer<true><<<EBLK, blk, 0, stream>>>(
        offs, dtS, att0, att1, RueA, RueB, RapA, RapB,
        We_ua + 260, We_au + 260, Qua, Pau, Wm_ua + 3200, Wm_au + 3200,
        agg_ue, partial);
    node_ue_kernel<false, true><<<N_UE / 256, blk, 0, stream>>>(
        x_ueA, agg_ue, Wu_ue + 4096, bu_ue + 64, nullptr, nullptr,
        We_ua + 264, We_au + 264,
        Wp1, bp1, Wp2, bp2,
        x_ueB, nullptr, RueA, RueB, out_ue);
    node_ap_kernel<false, true><<<N_AP, blk, 0, stream>>>(
        partial, x_apA, Wu_ap + 4096, bu_ap + 64, nullptr, nullptr,
        We_ua + 328, be_ua + 4, We_au + 328, be_au + 4,
        out_ap, nullptr, RapA, RapB);

    // ---- final edge update (layer 4), original order ----
    final_edge<<<NE / 256, blk, 0, stream>>>(
        src, dst, invS, att1, RueA, RueB, RapA, RapB,
        We_ua + 392, We_au + 392, out_eua, out_eau);
}

// Round 9
// 996.383 us; speedup vs baseline: 1.8565x; 1.8565x over previous
//
#include <hip/hip_runtime.h>
#include <math.h>

#define N_UE 16384
#define N_AP 128
#define NE   2097152
#define NSB  256                    // sort blocks
#define EPSB (NE / NSB)             // 8192 edges per sort block
#define CHS  8                      // src-side edges per chunk/thread
#define CHD  16                     // dst-side edges per chunk/thread
#define NEP  (NE + CHS * N_UE)      // padded src-sorted edge count 2228224
#define NCHU (NEP / CHS)            // 278528 src chunks
#define NEPD (NE + CHD * N_AP)      // padded dst-sorted edge count 2099200
#define NCHD (NEPD / CHD)           // 131200 dst chunks
#define NCHD_AL 131328              // 513*256

#define RFL(x) __int_as_float(__builtin_amdgcn_readfirstlane(__float_as_int(x)))

// ---------------------------------------------------------------------------
// prefill: sentinels in padded index arrays + chunk maps
// ---------------------------------------------------------------------------
__global__ __launch_bounds__(256) void prefill(
    int* __restrict__ dtS, int* __restrict__ srcD,
    int* __restrict__ cnS, int* __restrict__ cnD)
{
    int i = blockIdx.x * 256 + threadIdx.x;    // grid = NEP/256 = 8704
    dtS[i] = N_AP;                             // sentinel AP row (-1e30)
    if (i < NEPD) srcD[i] = N_UE;              // sentinel UE row (-1e30)
    if (i < NCHU) cnS[i] = -1;
    if (i < NCHD_AL) cnD[i] = -1;
}

// ---------------------------------------------------------------------------
// init tables + sentinel rows
// ---------------------------------------------------------------------------
__global__ __launch_bounds__(256) void init_kernel(
    const float* __restrict__ x_ue, const float* __restrict__ Wm1_ua,
    const float* __restrict__ bm1_ua, const float* __restrict__ bm1_au,
    float* __restrict__ Qua, float* __restrict__ Pau)
{
    int i = blockIdx.x * 256 + threadIdx.x;
    int d = i & 31;
    Qua[i] = fmaf(x_ue[i >> 5], Wm1_ua[d], bm1_ua[d]);
    if (i < N_AP * 32) Pau[i] = bm1_au[d];
    if (i < 32) { Qua[N_UE * 32 + i] = -1e30f; Pau[N_AP * 32 + i] = -1e30f; }
}

// ---------------------------------------------------------------------------
// src-sort (padded): histogram -> column scan -> chunk scan -> scatter
// ---------------------------------------------------------------------------
__global__ __launch_bounds__(256) void hist_src(
    const int* __restrict__ src, int* __restrict__ histS)
{
    __shared__ int h[N_UE];
    for (int i = threadIdx.x; i < N_UE; i += 256) h[i] = 0;
    __syncthreads();
    const int beg = blockIdx.x * EPSB;
    for (int e = beg + threadIdx.x; e < beg + EPSB; e += 256)
        atomicAdd(&h[src[e]], 1);
    __syncthreads();
    for (int i = threadIdx.x; i < N_UE; i += 256) histS[blockIdx.x * N_UE + i] = h[i];
}

__global__ __launch_bounds__(256) void colscan_kernel(
    const int* __restrict__ histS, int* __restrict__ baseS, int* __restrict__ cnt)
{
    const int u = blockIdx.x * 256 + threadIdx.x;
    int run = 0;
    for (int b = 0; b < NSB; ++b) {
        int t = histS[b * N_UE + u];
        baseS[b * N_UE + u] = run;
        run += t;
    }
    cnt[u] = run;
}

__global__ __launch_bounds__(256) void scan_src(
    const int* __restrict__ cnt, int* __restrict__ CU)
{
    __shared__ int ps[256];
    __shared__ int ps2[257];
    const int t = threadIdx.x;
    const int b0 = t * (N_UE / 256);
    int s = 0;
    for (int i = 0; i < N_UE / 256; ++i) s += (cnt[b0 + i] + CHS - 1) / CHS;
    ps[t] = s;
    __syncthreads();
    if (t == 0) {
        int r = 0;
        for (int i = 0; i < 256; ++i) { ps2[i] = r; r += ps[i]; }
        ps2[256] = r;
    }
    __syncthreads();
    int r = ps2[t];
    for (int i = 0; i < N_UE / 256; ++i) { CU[b0 + i] = r; r += (cnt[b0 + i] + CHS - 1) / CHS; }
    if (t == 255) CU[N_UE] = ps2[256];
}

__global__ __launch_bounds__(256) void scatter_src(
    const int* __restrict__ src, const int* __restrict__ dst,
    const float2* __restrict__ e0au,
    const int* __restrict__ baseS, const int* __restrict__ CU,
    int* __restrict__ dtS, float2* __restrict__ attS, int* __restrict__ invS)
{
    __shared__ int cursor[N_UE];
    const int b = blockIdx.x;
    for (int i = threadIdx.x; i < N_UE; i += 256)
        cursor[i] = CU[i] * CHS + baseS[b * N_UE + i];
    __syncthreads();
    const int beg = b * EPSB;
    for (int e = beg + threadIdx.x; e < beg + EPSB; e += 256) {
        int s = src[e];
        int pos = atomicAdd(&cursor[s], 1);
        dtS[pos] = dst[e];
        attS[pos] = e0au[e];
        invS[e] = pos;
    }
}

// ---------------------------------------------------------------------------
// dst-sort (padded, 128 bins)
// ---------------------------------------------------------------------------
__global__ __launch_bounds__(256) void hist_dst(
    const int* __restrict__ dst, int* __restrict__ histD)
{
    __shared__ int h[N_AP];
    if (threadIdx.x < N_AP) h[threadIdx.x] = 0;
    __syncthreads();
    const int beg = blockIdx.x * EPSB;
    for (int e = beg + threadIdx.x; e < beg + EPSB; e += 256)
        atomicAdd(&h[dst[e]], 1);
    __syncthreads();
    if (threadIdx.x < N_AP) histD[blockIdx.x * N_AP + threadIdx.x] = h[threadIdx.x];
}

__global__ __launch_bounds__(128) void scan_dst(
    const int* __restrict__ histD, int* __restrict__ offsD, int* __restrict__ CA)
{
    __shared__ int colTot[N_AP], colStart[N_AP];
    const int a = threadIdx.x;
    int run = 0;
    for (int b = 0; b < NSB; ++b) {
        offsD[b * N_AP + a] = run;
        run += histD[b * N_AP + a];
    }
    colTot[a] = run;
    __syncthreads();
    if (a == 0) {
        int r = 0;
        for (int i = 0; i < N_AP; ++i) {
            CA[i] = r;
            colStart[i] = r * CHD;
            r += (colTot[i] + CHD - 1) / CHD;
        }
        CA[N_AP] = r;
    }
    __syncthreads();
    const int st = colStart[a];
    for (int b = 0; b < NSB; ++b) offsD[b * N_AP + a] += st;
}

__global__ __launch_bounds__(256) void scatter_dst(
    const int* __restrict__ src, const int* __restrict__ dst,
    const float2* __restrict__ e0ua, const int* __restrict__ offsD,
    int* __restrict__ srcD, float2* __restrict__ attD, int* __restrict__ invD)
{
    __shared__ int cursor[N_AP];
    const int b = blockIdx.x;
    if (threadIdx.x < N_AP) cursor[threadIdx.x] = offsD[b * N_AP + threadIdx.x];
    __syncthreads();
    const int beg = b * EPSB;
    for (int e = beg + threadIdx.x; e < beg + EPSB; e += 256) {
        int dt = dst[e];
        int pos = atomicAdd(&cursor[dt], 1);
        srcD[pos] = src[e];
        attD[pos] = e0ua[e];
        invD[e] = pos;
    }
}

// ---------------------------------------------------------------------------
// chunk maps
// ---------------------------------------------------------------------------
__global__ __launch_bounds__(256) void build_map_src(
    const int* __restrict__ CU, int* __restrict__ cnS)
{
    const int u = blockIdx.x * 256 + threadIdx.x;   // grid 64
    const int c0 = CU[u], c1 = CU[u + 1];
    for (int c = c0; c < c1; ++c) cnS[c] = u;
}

__global__ __launch_bounds__(128) void build_map_dst(
    const int* __restrict__ CA, int* __restrict__ cnD)
{
    const int a = threadIdx.x;
    const int c0 = CA[a], c1 = CA[a + 1];
    for (int c = c0; c < c1; ++c) cnD[c] = a;
}

// ---------------------------------------------------------------------------
// pass_src: thread = 8-edge chunk of ONE UE node (padding-aligned).
// m_au = relu(Pau[dt] + e_au.w) -> 8xfloat4 register acc -> partialU row.
// EUPD e_au in place. No atomics, no LDS. Pads: dt=128 sentinel -> 0.
// ---------------------------------------------------------------------------
template<bool EUPD>
__global__ __launch_bounds__(256) void pass_src(
    const int* __restrict__ cnS, const int* __restrict__ dtS,
    float2* __restrict__ attS,
    const float2* __restrict__ RueB, const float2* __restrict__ RapB,
    const float* __restrict__ EcB,
    const float* __restrict__ Pau, const float* __restrict__ cw,
    float* __restrict__ partialU)
{
    const int ch = blockIdx.x * 256 + threadIdx.x;
    const int u = cnS[ch];
    if (u < 0) return;
    float w0v[32], w1v[32];
    #pragma unroll
    for (int d = 0; d < 32; ++d) { w0v[d] = RFL(cw[d]); w1v[d] = RFL(cw[32 + d]); }
    float d00 = 0.f, d01 = 0.f, d10 = 0.f, d11 = 0.f, rbx = 0.f, rby = 0.f;
    if constexpr (EUPD) {
        d00 = RFL(EcB[0]); d01 = RFL(EcB[1]); d10 = RFL(EcB[2]); d11 = RFL(EcB[3]);
        float2 r = RueB[u]; rbx = r.x; rby = r.y;
    }
    const float4* __restrict__ Pau4 = (const float4*)Pau;
    const int base = ch * CHS;
    float4 acc[8];
    #pragma unroll
    for (int q = 0; q < 8; ++q) acc[q] = make_float4(0.f, 0.f, 0.f, 0.f);
    #pragma unroll
    for (int j = 0; j < CHS; ++j) {
        int dt = dtS[base + j];
        float2 a = attS[base + j];
        if constexpr (EUPD) {
            float2 rp = RapB[dt];
            float m0 = fmaxf(rbx + rp.x + a.x * d00 + a.y * d10, 0.f);
            float m1 = fmaxf(rby + rp.y + a.x * d01 + a.y * d11, 0.f);
            a = make_float2(m0, m1);
            attS[base + j] = a;
        }
        const float4* pr = Pau4 + dt * 8;
        #pragma unroll
        for (int q = 0; q < 8; ++q) {
            float4 pv = pr[q];
            acc[q].x += fmaxf(fmaf(a.x, w0v[q*4+0], fmaf(a.y, w1v[q*4+0], pv.x)), 0.f);
            acc[q].y += fmaxf(fmaf(a.x, w0v[q*4+1], fmaf(a.y, w1v[q*4+1], pv.y)), 0.f);
            acc[q].z += fmaxf(fmaf(a.x, w0v[q*4+2], fmaf(a.y, w1v[q*4+2], pv.z)), 0.f);
            acc[q].w += fmaxf(fmaf(a.x, w0v[q*4+3], fmaf(a.y, w1v[q*4+3], pv.w)), 0.f);
        }
    }
    float4* pu = (float4*)(partialU + (size_t)ch * 32);
    #pragma unroll
    for (int q = 0; q < 8; ++q) pu[q] = acc[q];
}

// ---------------------------------------------------------------------------
// pass_dst: thread = 16-edge chunk of ONE AP node (dst-sorted, padded).
// m_ua = relu(Qua[s] + e_ua.u) -> register acc -> partialA row.
// EUPD e_ua in place. Pads: src=16384 sentinel -> 0.
// ---------------------------------------------------------------------------
template<bool EUPD>
__global__ __launch_bounds__(256) void pass_dst(
    const int* __restrict__ cnD, const int* __restrict__ srcD,
    float2* __restrict__ attD,
    const float2* __restrict__ RueA, const float2* __restrict__ RapA,
    const float* __restrict__ EcA,
    const float* __restrict__ Qua, const float* __restrict__ cu,
    float* __restrict__ partialA)
{
    const int ch = blockIdx.x * 256 + threadIdx.x;
    const int a = cnD[ch];
    if (a < 0) return;
    float u0v[32], u1v[32];
    #pragma unroll
    for (int d = 0; d < 32; ++d) { u0v[d] = RFL(cu[d]); u1v[d] = RFL(cu[32 + d]); }
    float c00 = 0.f, c01 = 0.f, c10 = 0.f, c11 = 0.f, rax = 0.f, ray = 0.f;
    if constexpr (EUPD) {
        c00 = RFL(EcA[0]); c01 = RFL(EcA[1]); c10 = RFL(EcA[2]); c11 = RFL(EcA[3]);
        float2 r = RapA[a]; rax = r.x; ray = r.y;
    }
    const float4* __restrict__ Qua4 = (const float4*)Qua;
    const int base = ch * CHD;
    float4 acc[8];
    #pragma unroll
    for (int q = 0; q < 8; ++q) acc[q] = make_float4(0.f, 0.f, 0.f, 0.f);
    #pragma unroll 4
    for (int j = 0; j < CHD; ++j) {
        int s = srcD[base + j];
        float2 a2 = attD[base + j];
        if constexpr (EUPD) {
            float2 ru = RueA[s];
            float n0 = fmaxf(rax + ru.x + a2.x * c00 + a2.y * c10, 0.f);
            float n1 = fmaxf(ray + ru.y + a2.x * c01 + a2.y * c11, 0.f);
            a2 = make_float2(n0, n1);
            attD[base + j] = a2;
        }
        const float4* qr = Qua4 + s * 8;
        #pragma unroll
        for (int q = 0; q < 8; ++q) {
            float4 qv = qr[q];
            acc[q].x += fmaxf(fmaf(a2.x, u0v[q*4+0], fmaf(a2.y, u1v[q*4+0], qv.x)), 0.f);
            acc[q].y += fmaxf(fmaf(a2.x, u0v[q*4+1], fmaf(a2.y, u1v[q*4+1], qv.y)), 0.f);
            acc[q].z += fmaxf(fmaf(a2.x, u0v[q*4+2], fmaf(a2.y, u1v[q*4+2], qv.z)), 0.f);
            acc[q].w += fmaxf(fmaf(a2.x, u0v[q*4+3], fmaf(a2.y, u1v[q*4+3], qv.w)), 0.f);
        }
    }
    float4* pa = (float4*)(partialA + (size_t)ch * 32);
    #pragma unroll
    for (int q = 0; q < 8; ++q) pa[q] = acc[q];
}

// ---------------------------------------------------------------------------
// reduce_ue: 32-lane group per node sums its chunk partial rows (coalesced).
// ---------------------------------------------------------------------------
__global__ __launch_bounds__(256) void reduce_ue(
    const int* __restrict__ CU, const float* __restrict__ partialU,
    float* __restrict__ agg_ue)
{
    const int g   = (blockIdx.x * 256 + threadIdx.x) >> 5;   // node, grid=2048
    const int dim = threadIdx.x & 31;
    const int c0 = CU[g], c1 = CU[g + 1];
    float acc = 0.f;
    for (int c = c0; c < c1; ++c) acc += partialU[(size_t)c * 32 + dim];
    agg_ue[g * 32 + dim] = acc;
}

// ---------------------------------------------------------------------------
// Final layer-4 edge update, original order.
// ---------------------------------------------------------------------------
__global__ __launch_bounds__(256) void final_edge(
    const int* __restrict__ src, const int* __restrict__ dst,
    const int* __restrict__ invS, const int* __restrict__ invD,
    const float2* __restrict__ attS, const float2* __restrict__ attD,
    const float2* __restrict__ RueA, const float2* __restrict__ RueB,
    const float2* __restrict__ RapA, const float2* __restrict__ RapB,
    const float* __restrict__ EcA, const float* __restrict__ EcB,
    float2* __restrict__ out_eua, float2* __restrict__ out_eau)
{
    const int e = blockIdx.x * 256 + threadIdx.x;
    const int s = src[e], dt = dst[e];
    float c00 = EcA[0], c01 = EcA[1], c10 = EcA[2], c11 = EcA[3];
    float d00 = EcB[0], d01 = EcB[1], d10 = EcB[2], d11 = EcB[3];
    float2 eua = attD[invD[e]];
    float2 eau = attS[invS[e]];
    float2 rA = RueA[s], pA = RapA[dt];
    float n0 = fmaxf(rA.x + pA.x + eua.x * c00 + eua.y * c10, 0.f);
    float n1 = fmaxf(rA.y + pA.y + eua.x * c01 + eua.y * c11, 0.f);
    float2 rB = RueB[s], pB = RapB[dt];
    float m0 = fmaxf(rB.x + pB.x + eau.x * d00 + eau.y * d10, 0.f);
    float m1 = fmaxf(rB.y + pB.y + eau.x * d01 + eau.y * d11, 0.f);
    out_eua[e] = make_float2(n0, n1);
    out_eau[e] = make_float2(m0, m1);
}

// ---------------------------------------------------------------------------
// UE node update + next-layer tables (+ power head for LAST)
// ---------------------------------------------------------------------------
template<bool FIRST, bool LAST>
__global__ __launch_bounds__(256) void node_ue_kernel(
    const float* __restrict__ x_prev, const float* __restrict__ agg_ue,
    const float* __restrict__ Wu, const float* __restrict__ bu,
    const float* __restrict__ Wm_next, const float* __restrict__ bm_next,
    const float* __restrict__ WeUa, const float* __restrict__ WeUb,
    const float* __restrict__ Wp1, const float* __restrict__ bp1,
    const float* __restrict__ Wp2, const float* __restrict__ bp2,
    float* __restrict__ x_new, float* __restrict__ Qua_next,
    float2* __restrict__ RueA, float2* __restrict__ RueB,
    float2* __restrict__ ue_out)
{
    constexpr int KIN = FIRST ? 33 : 64;
    __shared__ float Wu_s[64 * 32];
    __shared__ float Wm_s[32 * 32];
    __shared__ float WeA_s[64], WeB_s[64];
    __shared__ float bu_s[32], bm_s[32];
    __shared__ float Wp1_s[32 * 16], bp1_s[16], Wp2_s[16];

    const int tid = threadIdx.x;
    for (int i = tid; i < KIN * 32; i += 256) Wu_s[i] = Wu[i];
    if (tid < 32) bu_s[tid] = bu[tid];
    if (!LAST) {
        for (int i = tid; i < 1024; i += 256) Wm_s[i] = Wm_next[i];
        if (tid < 32) bm_s[tid] = bm_next[tid];
    }
    if (tid < 64) { WeA_s[tid] = WeUa[tid]; WeB_s[tid] = WeUb[tid]; }
    if (LAST) {
        for (int i = tid; i < 512; i += 256) Wp1_s[i] = Wp1[i];
        if (tid < 16) { bp1_s[tid] = bp1[tid]; Wp2_s[tid] = Wp2[tid]; }
    }
    __syncthreads();

    const int u = blockIdx.x * 256 + tid;
    float in[KIN];
    if (FIRST) {
        in[0] = x_prev[u];
        #pragma unroll
        for (int k = 0; k < 32; ++k) in[1 + k] = agg_ue[u * 32 + k];
    } else {
        #pragma unroll
        for (int k = 0; k < 32; ++k) in[k] = x_prev[u * 32 + k];
        #pragma unroll
        for (int k = 0; k < 32; ++k) in[32 + k] = agg_ue[u * 32 + k];
    }
    float out[32];
    #pragma unroll
    for (int d = 0; d < 32; ++d) {
        float acc = bu_s[d];
        #pragma unroll
        for (int k = 0; k < KIN; ++k) acc = fmaf(in[k], Wu_s[k * 32 + d], acc);
        out[d] = fmaxf(acc, 0.f);
    }
    #pragma unroll
    for (int d = 0; d < 32; ++d) x_new[u * 32 + d] = out[d];
    if (!LAST) {
        #pragma unroll
        for (int d = 0; d < 32; ++d) {
            float acc = bm_s[d];
            #pragma unroll
            for (int k = 0; k < 32; ++k) acc = fmaf(out[k], Wm_s[k * 32 + d], acc);
            Qua_next[u * 32 + d] = acc;
        }
    }
    float r0 = 0.f, r1 = 0.f, s0 = 0.f, s1 = 0.f;
    #pragma unroll
    for (int k = 0; k < 32; ++k) {
        r0 = fmaf(out[k], WeA_s[k * 2],     r0);
        r1 = fmaf(out[k], WeA_s[k * 2 + 1], r1);
        s0 = fmaf(out[k], WeB_s[k * 2],     s0);
        s1 = fmaf(out[k], WeB_s[k * 2 + 1], s1);
    }
    RueA[u] = make_float2(r0, r1);
    RueB[u] = make_float2(s0, s1);
    if (LAST) {
        float z = bp2[0];
        #pragma unroll
        for (int j = 0; j < 16; ++j) {
            float h = bp1_s[j];
            #pragma unroll
            for (int k = 0; k < 32; ++k) h = fmaf(out[k], Wp1_s[k * 16 + j], h);
            z = fmaf(fmaxf(h, 0.f), Wp2_s[j], z);
        }
        float pw = 1.f / (1.f + expf(-z));
        ue_out[u] = make_float2(out[0], pw);
    }
}

// ---------------------------------------------------------------------------
// AP: reduce chunk partials (CA ranges) -> agg_ap, node update, tables
// ---------------------------------------------------------------------------
template<bool FIRST, bool LAST>
__global__ __launch_bounds__(256) void node_ap_kernel(
    const float* __restrict__ partialA, const int* __restrict__ CA,
    const float* __restrict__ x_prev,
    const float* __restrict__ Wu, const float* __restrict__ bu,
    const float* __restrict__ Wm_next, const float* __restrict__ bm_next,
    const float* __restrict__ WeA, const float* __restrict__ beA,
    const float* __restrict__ WeB, const float* __restrict__ beB,
    float* __restrict__ x_new, float* __restrict__ Pau_next,
    float2* __restrict__ RapA, float2* __restrict__ RapB)
{
    __shared__ float red[256];
    __shared__ float agg_s[32];
    __shared__ float xnew_s[32];
    const int a = blockIdx.x, tid = threadIdx.x;
    const int d = tid & 31, p0 = tid >> 5;
    const int c0 = CA[a], c1 = CA[a + 1];
    float acc = 0.f;
    for (int p = c0 + p0; p < c1; p += 8)
        acc += partialA[(size_t)p * 32 + d];
    red[tid] = acc;
    __syncthreads();
    if (tid < 32) {
        float s = 0.f;
        #pragma unroll
        for (int i = 0; i < 8; ++i) s += red[i * 32 + tid];
        agg_s[tid] = s;
    }
    __syncthreads();
    if (tid < 32) {
        float acc2 = bu[d];
        if (FIRST) {
            #pragma unroll
            for (int k = 0; k < 32; ++k) acc2 = fmaf(agg_s[k], Wu[k * 32 + d], acc2);
        } else {
            #pragma unroll
            for (int k = 0; k < 32; ++k) acc2 = fmaf(x_prev[a * 32 + k], Wu[k * 32 + d], acc2);
            #pragma unroll
            for (int k = 0; k < 32; ++k) acc2 = fmaf(agg_s[k], Wu[(32 + k) * 32 + d], acc2);
        }
        float xn = fmaxf(acc2, 0.f);
        xnew_s[d] = xn;
        x_new[a * 32 + d] = xn;
    }
    __syncthreads();
    if (!LAST) {
        if (tid < 32) {
            float acc3 = bm_next[d];
            #pragma unroll
            for (int k = 0; k < 32; ++k) acc3 = fmaf(xnew_s[k], Wm_next[k * 32 + d], acc3);
            Pau_next[a * 32 + d] = acc3;
        }
    }
    if (tid == 0) {
        float q0 = beA[0], q1 = beA[1], t0 = beB[0], t1 = beB[1];
        #pragma unroll
        for (int k = 0; k < 32; ++k) {
            q0 = fmaf(xnew_s[k], WeA[k * 2],     q0);
            q1 = fmaf(xnew_s[k], WeA[k * 2 + 1], q1);
            t0 = fmaf(xnew_s[k], WeB[k * 2],     t0);
            t1 = fmaf(xnew_s[k], WeB[k * 2 + 1], t1);
        }
        RapA[a] = make_float2(q0, q1);
        RapB[a] = make_float2(t0, t1);
    }
}

// ---------------------------------------------------------------------------
extern "C" void kernel_launch(void* const* d_in, const int* in_sizes, int n_in,
                              void* d_out_v, int out_size, void* d_ws, size_t ws_size,
                              hipStream_t stream)
{
    const float*  x_ue   = (const float*)d_in[0];
    const float2* e0ua   = (const float2*)d_in[1];
    const float2* e0au   = (const float2*)d_in[2];
    const int*    src    = (const int*)d_in[3];
    const int*    dst    = (const int*)d_in[4];
    const float* Wm1_ua = (const float*)d_in[5];
    const float* bm1_ua = (const float*)d_in[6];
    const float* Wm1_au = (const float*)d_in[7];
    const float* bm1_au = (const float*)d_in[8];
    const float* Wu1_ap = (const float*)d_in[9];
    const float* bu1_ap = (const float*)d_in[10];
    const float* Wu1_ue = (const float*)d_in[11];
    const float* bu1_ue = (const float*)d_in[12];
    const float* We1_ua = (const float*)d_in[13];
    const float* be1_ua = (const float*)d_in[14];
    const float* We1_au = (const float*)d_in[15];
    const float* be1_au = (const float*)d_in[16];
    const float* Wm_ua  = (const float*)d_in[17];
    const float* bm_ua  = (const float*)d_in[18];
    const float* Wm_au  = (const float*)d_in[19];
    const float* bm_au  = (const float*)d_in[20];
    const float* Wu_ap  = (const float*)d_in[21];
    const float* bu_ap  = (const float*)d_in[22];
    const float* Wu_ue  = (const float*)d_in[23];
    const float* bu_ue  = (const float*)d_in[24];
    const float* We_ua  = (const float*)d_in[25];
    const float* be_ua  = (const float*)d_in[26];
    const float* We_au  = (const float*)d_in[27];
    const float* be_au  = (const float*)d_in[28];
    const float* Wp1    = (const float*)d_in[29];
    const float* bp1    = (const float*)d_in[30];
    const float* Wp2    = (const float*)d_in[31];
    const float* bp2    = (const float*)d_in[32];

    float*  outp    = (float*)d_out_v;
    float2* out_ue  = (float2*)outp;                              // [16384][2]
    float*  out_ap  = outp + N_UE * 2;                            // [128][32]
    float2* out_eua = (float2*)(outp + N_UE * 2 + N_AP * 32);     // [E][2]
    float2* out_eau = (float2*)(outp + N_UE * 2 + N_AP * 32 + (size_t)NE * 2);

    float* ws = (float*)d_ws;
    float* x_ueA  = ws;          ws += N_UE * 32;
    float* x_ueB  = ws;          ws += N_UE * 32;
    float* x_apA  = ws;          ws += N_AP * 32;
    float* x_apB  = ws;          ws += N_AP * 32;
    float* agg_ue = ws;          ws += N_UE * 32;
    float* Qua    = ws;          ws += (N_UE + 1) * 32;
    float* Pau    = ws;          ws += (N_AP + 1) * 32;
    float2* RueA  = (float2*)ws; ws += (N_UE + 2) * 2;
    float2* RueB  = (float2*)ws; ws += (N_UE + 2) * 2;
    float2* RapA  = (float2*)ws; ws += (N_AP + 2) * 2;
    float2* RapB  = (float2*)ws; ws += (N_AP + 2) * 2;
    int* cnt   = (int*)ws;       ws += N_UE;
    int* CU    = (int*)ws;       ws += N_UE + 4;
    int* histD = (int*)ws;       ws += NSB * N_AP;
    int* offsD = (int*)ws;       ws += NSB * N_AP;
    int* CA    = (int*)ws;       ws += N_AP + 4;
    int* cnS   = (int*)ws;       ws += NCHU;
    int* cnD   = (int*)ws;       ws += NCHD_AL;
    int* invS  = (int*)ws;       ws += NE;
    int* invD  = (int*)ws;       ws += NE;
    int* dtS   = (int*)ws;       ws += NEP;
    int* srcD  = (int*)ws;       ws += NEPD;
    float2* attS = (float2*)ws;  ws += (size_t)NEP * 2;
    float2* attD = (float2*)ws;  ws += (size_t)NEPD * 2;
    float* partialU = ws;        ws += (size_t)NCHU * 32;         // 35.6 MB
    float* partialA = ws;        ws += (size_t)NCHD_AL * 32;      // 16.8 MB
    int* histS = (int*)partialU;                        // 16 MB alias
    int* baseS = (int*)(partialU + (size_t)NSB * N_UE); // 16 MB alias

    dim3 blk(256);

    // ---- prefill sentinels + sorts ----
    prefill<<<NEP / 256, blk, 0, stream>>>(dtS, srcD, cnS, cnD);
    hist_src<<<NSB, blk, 0, stream>>>(src, histS);
    colscan_kernel<<<N_UE / 256, blk, 0, stream>>>(histS, baseS, cnt);
    scan_src<<<1, blk, 0, stream>>>(cnt, CU);
    scatter_src<<<NSB, blk, 0, stream>>>(src, dst, e0au, baseS, CU, dtS, attS, invS);
    hist_dst<<<NSB, blk, 0, stream>>>(dst, histD);
    scan_dst<<<1, dim3(128), 0, stream>>>(histD, offsD, CA);
    scatter_dst<<<NSB, blk, 0, stream>>>(src, dst, e0ua, offsD, srcD, attD, invD);
    build_map_src<<<N_UE / 256, blk, 0, stream>>>(CU, cnS);
    build_map_dst<<<1, dim3(128), 0, stream>>>(CA, cnD);

    init_kernel<<<N_UE * 32 / 256, blk, 0, stream>>>(x_ue, Wm1_ua, bm1_ua, bm1_au, Qua, Pau);

    // ---- layer 1 ----
    pass_src<false><<<NCHU / 256, blk, 0, stream>>>(
        cnS, dtS, attS, nullptr, nullptr, nullptr, Pau, Wm1_au, partialU);
    pass_dst<false><<<NCHD_AL / 256, blk, 0, stream>>>(
        cnD, srcD, attD, nullptr, nullptr, nullptr, Qua, Wm1_ua + 32, partialA);
    reduce_ue<<<N_UE * 32 / 256, blk, 0, stream>>>(CU, partialU, agg_ue);
    node_ue_kernel<true, false><<<N_UE / 256, blk, 0, stream>>>(
        x_ue, agg_ue, Wu1_ue, bu1_ue, Wm_ua, bm_ua, We1_ua, We1_au,
        nullptr, nullptr, nullptr, nullptr,
        x_ueA, Qua, RueA, RueB, nullptr);
    node_ap_kernel<true, false><<<N_AP, blk, 0, stream>>>(
        partialA, CA, nullptr, Wu1_ap, bu1_ap, Wm_au, bm_au,
        We1_ua + 64, be1_ua, We1_au + 64, be1_au,
        x_apA, Pau, RapA, RapB);

    // ---- layer 2 (edge-update 1 fused) ----
    pass_src<true><<<NCHU / 256, blk, 0, stream>>>(
        cnS, dtS, attS, RueB, RapB, We1_au + 128, Pau, Wm_au + 1024, partialU);
    pass_dst<true><<<NCHD_AL / 256, blk, 0, stream>>>(
        cnD, srcD, attD, RueA, RapA, We1_ua + 128, Qua, Wm_ua + 1024, partialA);
    reduce_ue<<<N_UE * 32 / 256, blk, 0, stream>>>(CU, partialU, agg_ue);
    node_ue_kernel<false, false><<<N_UE / 256, blk, 0, stream>>>(
        x_ueA, agg_ue, Wu_ue, bu_ue, Wm_ua + 1088, bm_ua + 32, We_ua, We_au,
        nullptr, nullptr, nullptr, nullptr,
        x_ueB, Qua, RueA, RueB, nullptr);
    node_ap_kernel<false, false><<<N_AP, blk, 0, stream>>>(
        partialA, CA, x_apA, Wu_ap, bu_ap, Wm_au + 1088, bm_au + 32,
        We_ua + 64, be_ua, We_au + 64, be_au,
        x_apB, Pau, RapA, RapB);

    // ---- layer 3 (edge-update 2 fused) ----
    pass_src<true><<<NCHU / 256, blk, 0, stream>>>(
        cnS, dtS, attS, RueB, RapB, We_au + 128, Pau, Wm_au + 2112, partialU);
    pass_dst<true><<<NCHD_AL / 256, blk, 0, stream>>>(
        cnD, srcD, attD, RueA, RapA, We_ua + 128, Qua, Wm_ua + 2112, partialA);
    reduce_ue<<<N_UE * 32 / 256, blk, 0, stream>>>(CU, partialU, agg_ue);
    node_ue_kernel<false, false><<<N_UE / 256, blk, 0, stream>>>(
        x_ueB, agg_ue, Wu_ue + 2048, bu_ue + 32, Wm_ua + 2176, bm_ua + 64,
        We_ua + 132, We_au + 132,
        nullptr, nullptr, nullptr, nullptr,
        x_ueA, Qua, RueA, RueB, nullptr);
    node_ap_kernel<false, false><<<N_AP, blk, 0, stream>>>(
        partialA, CA, x_apB, Wu_ap + 2048, bu_ap + 32, Wm_au + 2176, bm_au + 64,
        We_ua + 196, be_ua + 2, We_au + 196, be_au + 2,
        x_apA, Pau, RapA, RapB);

    // ---- layer 4 (edge-update 3 fused) ----
    pass_src<true><<<NCHU / 256, blk, 0, stream>>>(
        cnS, dtS, attS, RueB, RapB, We_au + 260, Pau, Wm_au + 3200, partialU);
    pass_dst<true><<<NCHD_AL / 256, blk, 0, stream>>>(
        cnD, srcD, attD, RueA, RapA, We_ua + 260, Qua, Wm_ua + 3200, partialA);
    reduce_ue<<<N_UE * 32 / 256, blk, 0, stream>>>(CU, partialU, agg_ue);
    node_ue_kernel<false, true><<<N_UE / 256, blk, 0, stream>>>(
        x_ueA, agg_ue, Wu_ue + 4096, bu_ue + 64, nullptr, nullptr,
        We_ua + 264, We_au + 264,
        Wp1, bp1, Wp2, bp2,
        x_ueB, nullptr, RueA, RueB, out_ue);
    node_ap_kernel<false, true><<<N_AP, blk, 0, stream>>>(
        partialA, CA, x_apA, Wu_ap + 4096, bu_ap + 64, nullptr, nullptr,
        We_ua + 328, be_ua + 4, We_au + 328, be_au + 4,
        out_ap, nullptr, RapA, RapB);

    // ---- final edge update (layer 4), original order ----
    final_edge<<<NE / 256, blk, 0, stream>>>(
        src, dst, invS, invD, attS, attD,
        RueA, RueB, RapA, RapB,
        We_ua + 392, We_au + 392, out_eua, out_eau);
}

// Round 10
// 891.888 us; speedup vs baseline: 2.0740x; 1.1172x over previous
//
#include <hip/hip_runtime.h>
#include <math.h>

#define N_UE 16384
#define N_AP 128
#define NE   2097152
#define NSB  256                    // sort blocks
#define EPSB (NE / NSB)             // 8192 edges per sort block
#define NHALF (N_UE / 2)            // scatter sub-pass node range
#define CHS  8                      // src-side edges per chunk/thread
#define CHD  16                     // dst-side edges per chunk/thread
#define NEP  (NE + CHS * N_UE)      // padded src-sorted edge count 2228224
#define NCHU (NEP / CHS)            // 278528 src chunks
#define NEPD (NE + CHD * N_AP)      // padded dst-sorted edge count 2099200
#define NCHD_AL 131328              // 513*256 dst chunks (padded)
#define SRC_BLKS (NCHU / 256)       // 1088
#define DST_BLKS (NCHD_AL / 256)    // 513

#define RFL(x) __int_as_float(__builtin_amdgcn_readfirstlane(__float_as_int(x)))

// ---------------------------------------------------------------------------
// prefill: sentinels in padded index arrays + chunk maps
// ---------------------------------------------------------------------------
__global__ __launch_bounds__(256) void prefill(
    int* __restrict__ dtS, int* __restrict__ srcD,
    int* __restrict__ cnS, int* __restrict__ cnD)
{
    int i = blockIdx.x * 256 + threadIdx.x;    // grid = NEP/256
    dtS[i] = N_AP;                             // sentinel AP row (-1e30)
    if (i < NEPD) srcD[i] = N_UE;              // sentinel UE row (-1e30)
    if (i < NCHU) cnS[i] = -1;
    if (i < NCHD_AL) cnD[i] = -1;
}

// ---------------------------------------------------------------------------
// init tables + sentinel rows
// ---------------------------------------------------------------------------
__global__ __launch_bounds__(256) void init_kernel(
    const float* __restrict__ x_ue, const float* __restrict__ Wm1_ua,
    const float* __restrict__ bm1_ua, const float* __restrict__ bm1_au,
    float* __restrict__ Qua, float* __restrict__ Pau)
{
    int i = blockIdx.x * 256 + threadIdx.x;
    int d = i & 31;
    Qua[i] = fmaf(x_ue[i >> 5], Wm1_ua[d], bm1_ua[d]);
    if (i < N_AP * 32) Pau[i] = bm1_au[d];
    if (i < 32) { Qua[N_UE * 32 + i] = -1e30f; Pau[N_AP * 32 + i] = -1e30f; }
}

// ---------------------------------------------------------------------------
// fused histograms: src (u16-packed, 32KB LDS) + dst (512B LDS)
// ---------------------------------------------------------------------------
__global__ __launch_bounds__(256) void hist_both(
    const int* __restrict__ src, const int* __restrict__ dst,
    unsigned short* __restrict__ histS, int* __restrict__ histD)
{
    __shared__ unsigned int h32[N_UE / 2];   // 2 x u16 per word, 32KB
    __shared__ int hd[N_AP];
    const int tid = threadIdx.x, b = blockIdx.x;
    for (int i = tid; i < N_UE / 2; i += 256) h32[i] = 0u;
    if (tid < N_AP) hd[tid] = 0;
    __syncthreads();
    const int beg = b * EPSB;
    for (int e = beg + tid; e < beg + EPSB; e += 256) {
        int s = src[e];
        atomicAdd(&h32[s >> 1], 1u << ((s & 1) * 16));
        atomicAdd(&hd[dst[e]], 1);
    }
    __syncthreads();
    for (int i = tid; i < N_UE; i += 256)
        histS[(size_t)b * N_UE + i] =
            (unsigned short)((h32[i >> 1] >> ((i & 1) * 16)) & 0xffffu);
    if (tid < N_AP) histD[b * N_AP + tid] = hd[tid];
}

__global__ __launch_bounds__(256) void colscan_kernel(
    const unsigned short* __restrict__ histS,
    unsigned short* __restrict__ baseS, int* __restrict__ cnt)
{
    const int u = blockIdx.x * 256 + threadIdx.x;
    int run = 0;
    for (int b = 0; b < NSB; ++b) {
        int t = histS[(size_t)b * N_UE + u];
        baseS[(size_t)b * N_UE + u] = (unsigned short)run;
        run += t;
    }
    cnt[u] = run;
}

__global__ __launch_bounds__(256) void scan_src(
    const int* __restrict__ cnt, int* __restrict__ CU)
{
    __shared__ int ps[256];
    __shared__ int ps2[257];
    const int t = threadIdx.x;
    const int b0 = t * (N_UE / 256);
    int s = 0;
    for (int i = 0; i < N_UE / 256; ++i) s += (cnt[b0 + i] + CHS - 1) / CHS;
    ps[t] = s;
    __syncthreads();
    if (t == 0) {
        int r = 0;
        for (int i = 0; i < 256; ++i) { ps2[i] = r; r += ps[i]; }
        ps2[256] = r;
    }
    __syncthreads();
    int r = ps2[t];
    for (int i = 0; i < N_UE / 256; ++i) { CU[b0 + i] = r; r += (cnt[b0 + i] + CHS - 1) / CHS; }
    if (t == 255) CU[N_UE] = ps2[256];
}

__global__ __launch_bounds__(128) void scan_dst(
    const int* __restrict__ histD, int* __restrict__ offsD, int* __restrict__ CA)
{
    __shared__ int colTot[N_AP], colStart[N_AP];
    const int a = threadIdx.x;
    int run = 0;
    for (int b = 0; b < NSB; ++b) {
        offsD[b * N_AP + a] = run;
        run += histD[b * N_AP + a];
    }
    colTot[a] = run;
    __syncthreads();
    if (a == 0) {
        int r = 0;
        for (int i = 0; i < N_AP; ++i) {
            CA[i] = r;
            colStart[i] = r * CHD;
            r += (colTot[i] + CHD - 1) / CHD;
        }
        CA[N_AP] = r;
    }
    __syncthreads();
    const int st = colStart[a];
    for (int b = 0; b < NSB; ++b) offsD[b * N_AP + a] += st;
}

// ---------------------------------------------------------------------------
// fused scatter: 2 sub-passes over src node-halves (32KB cursor) + dst
// scatter folded into pass 0 (512B cursor).
// ---------------------------------------------------------------------------
__global__ __launch_bounds__(256) void scatter_both(
    const int* __restrict__ src, const int* __restrict__ dst,
    const float2* __restrict__ e0ua, const float2* __restrict__ e0au,
    const unsigned short* __restrict__ baseS, const int* __restrict__ CU,
    const int* __restrict__ offsD,
    int* __restrict__ dtS, float2* __restrict__ attS, int* __restrict__ invS,
    int* __restrict__ srcD, float2* __restrict__ attD, int* __restrict__ invD)
{
    __shared__ int cursor[NHALF];    // 32KB
    __shared__ int cursord[N_AP];
    const int tid = threadIdx.x, b = blockIdx.x;
    const int beg = b * EPSB;
    if (tid < N_AP) cursord[tid] = offsD[b * N_AP + tid];
    for (int p = 0; p < 2; ++p) {
        const int lo = p * NHALF;
        for (int i = tid; i < NHALF; i += 256)
            cursor[i] = CU[lo + i] * CHS + (int)baseS[(size_t)b * N_UE + lo + i];
        __syncthreads();
        for (int e = beg + tid; e < beg + EPSB; e += 256) {
            int s = src[e];
            int dt = dst[e];
            if (p == 0) {
                int posd = atomicAdd(&cursord[dt], 1);
                srcD[posd] = s;
                attD[posd] = e0ua[e];
                invD[e] = posd;
            }
            if (s >= lo && s < lo + NHALF) {
                int pos = atomicAdd(&cursor[s - lo], 1);
                dtS[pos] = dt;
                attS[pos] = e0au[e];
                invS[e] = pos;
            }
        }
        __syncthreads();
    }
}

// ---------------------------------------------------------------------------
// chunk maps
// ---------------------------------------------------------------------------
__global__ __launch_bounds__(256) void build_map_src(
    const int* __restrict__ CU, int* __restrict__ cnS)
{
    const int u = blockIdx.x * 256 + threadIdx.x;   // grid 64
    const int c0 = CU[u], c1 = CU[u + 1];
    for (int c = c0; c < c1; ++c) cnS[c] = u;
}

__global__ __launch_bounds__(128) void build_map_dst(
    const int* __restrict__ CA, int* __restrict__ cnD)
{
    const int a = threadIdx.x;
    const int c0 = CA[a], c1 = CA[a + 1];
    for (int c = c0; c < c1; ++c) cnD[c] = a;
}

// ---------------------------------------------------------------------------
// fused edge pass: blocks [0,SRC_BLKS) = src chunks; rest = dst chunks.
// src: thread = 8-edge chunk of ONE UE node -> partialU row (no atomics).
// dst: thread = 16-edge chunk of ONE AP node -> partialA row (no atomics).
// ---------------------------------------------------------------------------
template<bool EUPD>
__global__ __launch_bounds__(256) void pass_both(
    const int* __restrict__ cnS, const int* __restrict__ dtS,
    float2* __restrict__ attS,
    const int* __restrict__ cnD, const int* __restrict__ srcD,
    float2* __restrict__ attD,
    const float2* __restrict__ RueA, const float2* __restrict__ RueB,
    const float2* __restrict__ RapA, const float2* __restrict__ RapB,
    const float* __restrict__ EcA, const float* __restrict__ EcB,
    const float* __restrict__ Qua, const float* __restrict__ Pau,
    const float* __restrict__ cu, const float* __restrict__ cw,
    float* __restrict__ partialU, float* __restrict__ partialA)
{
    if (blockIdx.x < SRC_BLKS) {
        const int ch = blockIdx.x * 256 + threadIdx.x;
        const int u = cnS[ch];
        if (u < 0) return;
        float w0v[32], w1v[32];
        #pragma unroll
        for (int d = 0; d < 32; ++d) { w0v[d] = RFL(cw[d]); w1v[d] = RFL(cw[32 + d]); }
        float d00 = 0.f, d01 = 0.f, d10 = 0.f, d11 = 0.f, rbx = 0.f, rby = 0.f;
        if constexpr (EUPD) {
            d00 = RFL(EcB[0]); d01 = RFL(EcB[1]); d10 = RFL(EcB[2]); d11 = RFL(EcB[3]);
            float2 r = RueB[u]; rbx = r.x; rby = r.y;
        }
        const float4* __restrict__ Pau4 = (const float4*)Pau;
        const int base = ch * CHS;
        float4 acc[8];
        #pragma unroll
        for (int q = 0; q < 8; ++q) acc[q] = make_float4(0.f, 0.f, 0.f, 0.f);
        #pragma unroll
        for (int j = 0; j < CHS; ++j) {
            int dt = dtS[base + j];
            float2 a = attS[base + j];
            if constexpr (EUPD) {
                float2 rp = RapB[dt];
                float m0 = fmaxf(rbx + rp.x + a.x * d00 + a.y * d10, 0.f);
                float m1 = fmaxf(rby + rp.y + a.x * d01 + a.y * d11, 0.f);
                a = make_float2(m0, m1);
                attS[base + j] = a;
            }
            const float4* pr = Pau4 + dt * 8;
            #pragma unroll
            for (int q = 0; q < 8; ++q) {
                float4 pv = pr[q];
                acc[q].x += fmaxf(fmaf(a.x, w0v[q*4+0], fmaf(a.y, w1v[q*4+0], pv.x)), 0.f);
                acc[q].y += fmaxf(fmaf(a.x, w0v[q*4+1], fmaf(a.y, w1v[q*4+1], pv.y)), 0.f);
                acc[q].z += fmaxf(fmaf(a.x, w0v[q*4+2], fmaf(a.y, w1v[q*4+2], pv.z)), 0.f);
                acc[q].w += fmaxf(fmaf(a.x, w0v[q*4+3], fmaf(a.y, w1v[q*4+3], pv.w)), 0.f);
            }
        }
        float4* pu = (float4*)(partialU + (size_t)ch * 32);
        #pragma unroll
        for (int q = 0; q < 8; ++q) pu[q] = acc[q];
    } else {
        const int ch = (blockIdx.x - SRC_BLKS) * 256 + threadIdx.x;
        const int a = cnD[ch];
        if (a < 0) return;
        float u0v[32], u1v[32];
        #pragma unroll
        for (int d = 0; d < 32; ++d) { u0v[d] = RFL(cu[d]); u1v[d] = RFL(cu[32 + d]); }
        float c00 = 0.f, c01 = 0.f, c10 = 0.f, c11 = 0.f, rax = 0.f, ray = 0.f;
        if constexpr (EUPD) {
            c00 = RFL(EcA[0]); c01 = RFL(EcA[1]); c10 = RFL(EcA[2]); c11 = RFL(EcA[3]);
            float2 r = RapA[a]; rax = r.x; ray = r.y;
        }
        const float4* __restrict__ Qua4 = (const float4*)Qua;
        const int base = ch * CHD;
        float4 acc[8];
        #pragma unroll
        for (int q = 0; q < 8; ++q) acc[q] = make_float4(0.f, 0.f, 0.f, 0.f);
        #pragma unroll 4
        for (int j = 0; j < CHD; ++j) {
            int s = srcD[base + j];
            float2 a2 = attD[base + j];
            if constexpr (EUPD) {
                float2 ru = RueA[s];
                float n0 = fmaxf(rax + ru.x + a2.x * c00 + a2.y * c10, 0.f);
                float n1 = fmaxf(ray + ru.y + a2.x * c01 + a2.y * c11, 0.f);
                a2 = make_float2(n0, n1);
                attD[base + j] = a2;
            }
            const float4* qr = Qua4 + s * 8;
            #pragma unroll
            for (int q = 0; q < 8; ++q) {
                float4 qv = qr[q];
                acc[q].x += fmaxf(fmaf(a2.x, u0v[q*4+0], fmaf(a2.y, u1v[q*4+0], qv.x)), 0.f);
                acc[q].y += fmaxf(fmaf(a2.x, u0v[q*4+1], fmaf(a2.y, u1v[q*4+1], qv.y)), 0.f);
                acc[q].z += fmaxf(fmaf(a2.x, u0v[q*4+2], fmaf(a2.y, u1v[q*4+2], qv.z)), 0.f);
                acc[q].w += fmaxf(fmaf(a2.x, u0v[q*4+3], fmaf(a2.y, u1v[q*4+3], qv.w)), 0.f);
            }
        }
        float4* pa = (float4*)(partialA + (size_t)ch * 32);
        #pragma unroll
        for (int q = 0; q < 8; ++q) pa[q] = acc[q];
    }
}

// ---------------------------------------------------------------------------
// reduce_ue: 32-lane group per node sums its chunk partial rows.
// ---------------------------------------------------------------------------
__global__ __launch_bounds__(256) void reduce_ue(
    const int* __restrict__ CU, const float* __restrict__ partialU,
    float* __restrict__ agg_ue)
{
    const int g   = (blockIdx.x * 256 + threadIdx.x) >> 5;   // node, grid=2048
    const int dim = threadIdx.x & 31;
    const int c0 = CU[g], c1 = CU[g + 1];
    float acc = 0.f;
    for (int c = c0; c < c1; ++c) acc += partialU[(size_t)c * 32 + dim];
    agg_ue[g * 32 + dim] = acc;
}

// ---------------------------------------------------------------------------
// Final layer-4 edge update, original order.
// ---------------------------------------------------------------------------
__global__ __launch_bounds__(256) void final_edge(
    const int* __restrict__ src, const int* __restrict__ dst,
    const int* __restrict__ invS, const int* __restrict__ invD,
    const float2* __restrict__ attS, const float2* __restrict__ attD,
    const float2* __restrict__ RueA, const float2* __restrict__ RueB,
    const float2* __restrict__ RapA, const float2* __restrict__ RapB,
    const float* __restrict__ EcA, const float* __restrict__ EcB,
    float2* __restrict__ out_eua, float2* __restrict__ out_eau)
{
    const int e = blockIdx.x * 256 + threadIdx.x;
    const int s = src[e], dt = dst[e];
    float c00 = EcA[0], c01 = EcA[1], c10 = EcA[2], c11 = EcA[3];
    float d00 = EcB[0], d01 = EcB[1], d10 = EcB[2], d11 = EcB[3];
    float2 eua = attD[invD[e]];
    float2 eau = attS[invS[e]];
    float2 rA = RueA[s], pA = RapA[dt];
    float n0 = fmaxf(rA.x + pA.x + eua.x * c00 + eua.y * c10, 0.f);
    float n1 = fmaxf(rA.y + pA.y + eua.x * c01 + eua.y * c11, 0.f);
    float2 rB = RueB[s], pB = RapB[dt];
    float m0 = fmaxf(rB.x + pB.x + eau.x * d00 + eau.y * d10, 0.f);
    float m1 = fmaxf(rB.y + pB.y + eau.x * d01 + eau.y * d11, 0.f);
    out_eua[e] = make_float2(n0, n1);
    out_eau[e] = make_float2(m0, m1);
}

// ---------------------------------------------------------------------------
// UE node update + next-layer tables (+ power head for LAST). 64-thr blocks.
// ---------------------------------------------------------------------------
template<bool FIRST, bool LAST>
__global__ __launch_bounds__(64) void node_ue_kernel(
    const float* __restrict__ x_prev, const float* __restrict__ agg_ue,
    const float* __restrict__ Wu, const float* __restrict__ bu,
    const float* __restrict__ Wm_next, const float* __restrict__ bm_next,
    const float* __restrict__ WeUa, const float* __restrict__ WeUb,
    const float* __restrict__ Wp1, const float* __restrict__ bp1,
    const float* __restrict__ Wp2, const float* __restrict__ bp2,
    float* __restrict__ x_new, float* __restrict__ Qua_next,
    float2* __restrict__ RueA, float2* __restrict__ RueB,
    float2* __restrict__ ue_out)
{
    constexpr int KIN = FIRST ? 33 : 64;
    __shared__ float Wu_s[64 * 32];
    __shared__ float Wm_s[32 * 32];
    __shared__ float WeA_s[64], WeB_s[64];
    __shared__ float bu_s[32], bm_s[32];
    __shared__ float Wp1_s[32 * 16], bp1_s[16], Wp2_s[16];

    const int tid = threadIdx.x;
    for (int i = tid; i < KIN * 32; i += 64) Wu_s[i] = Wu[i];
    if (tid < 32) bu_s[tid] = bu[tid];
    if (!LAST) {
        for (int i = tid; i < 1024; i += 64) Wm_s[i] = Wm_next[i];
        if (tid < 32) bm_s[tid] = bm_next[tid];
    }
    { WeA_s[tid] = WeUa[tid]; WeB_s[tid] = WeUb[tid]; }
    if (LAST) {
        for (int i = tid; i < 512; i += 64) Wp1_s[i] = Wp1[i];
        if (tid < 16) { bp1_s[tid] = bp1[tid]; Wp2_s[tid] = Wp2[tid]; }
    }
    __syncthreads();

    const int u = blockIdx.x * 64 + tid;
    float in[KIN];
    if (FIRST) {
        in[0] = x_prev[u];
        #pragma unroll
        for (int k = 0; k < 32; ++k) in[1 + k] = agg_ue[u * 32 + k];
    } else {
        #pragma unroll
        for (int k = 0; k < 32; ++k) in[k] = x_prev[u * 32 + k];
        #pragma unroll
        for (int k = 0; k < 32; ++k) in[32 + k] = agg_ue[u * 32 + k];
    }
    float out[32];
    #pragma unroll
    for (int d = 0; d < 32; ++d) {
        float acc = bu_s[d];
        #pragma unroll
        for (int k = 0; k < KIN; ++k) acc = fmaf(in[k], Wu_s[k * 32 + d], acc);
        out[d] = fmaxf(acc, 0.f);
    }
    #pragma unroll
    for (int d = 0; d < 32; ++d) x_new[u * 32 + d] = out[d];
    if (!LAST) {
        #pragma unroll
        for (int d = 0; d < 32; ++d) {
            float acc = bm_s[d];
            #pragma unroll
            for (int k = 0; k < 32; ++k) acc = fmaf(out[k], Wm_s[k * 32 + d], acc);
            Qua_next[u * 32 + d] = acc;
        }
    }
    float r0 = 0.f, r1 = 0.f, s0 = 0.f, s1 = 0.f;
    #pragma unroll
    for (int k = 0; k < 32; ++k) {
        r0 = fmaf(out[k], WeA_s[k * 2],     r0);
        r1 = fmaf(out[k], WeA_s[k * 2 + 1], r1);
        s0 = fmaf(out[k], WeB_s[k * 2],     s0);
        s1 = fmaf(out[k], WeB_s[k * 2 + 1], s1);
    }
    RueA[u] = make_float2(r0, r1);
    RueB[u] = make_float2(s0, s1);
    if (LAST) {
        float z = bp2[0];
        #pragma unroll
        for (int j = 0; j < 16; ++j) {
            float h = bp1_s[j];
            #pragma unroll
            for (int k = 0; k < 32; ++k) h = fmaf(out[k], Wp1_s[k * 16 + j], h);
            z = fmaf(fmaxf(h, 0.f), Wp2_s[j], z);
        }
        float pw = 1.f / (1.f + expf(-z));
        ue_out[u] = make_float2(out[0], pw);
    }
}

// ---------------------------------------------------------------------------
// AP: reduce chunk partials (CA ranges) -> agg_ap, node update, tables
// ---------------------------------------------------------------------------
template<bool FIRST, bool LAST>
__global__ __launch_bounds__(256) void node_ap_kernel(
    const float* __restrict__ partialA, const int* __restrict__ CA,
    const float* __restrict__ x_prev,
    const float* __restrict__ Wu, const float* __restrict__ bu,
    const float* __restrict__ Wm_next, const float* __restrict__ bm_next,
    const float* __restrict__ WeA, const float* __restrict__ beA,
    const float* __restrict__ WeB, const float* __restrict__ beB,
    float* __restrict__ x_new, float* __restrict__ Pau_next,
    float2* __restrict__ RapA, float2* __restrict__ RapB)
{
    __shared__ float red[256];
    __shared__ float agg_s[32];
    __shared__ float xnew_s[32];
    const int a = blockIdx.x, tid = threadIdx.x;
    const int d = tid & 31, p0 = tid >> 5;
    const int c0 = CA[a], c1 = CA[a + 1];
    float acc = 0.f;
    for (int p = c0 + p0; p < c1; p += 8)
        acc += partialA[(size_t)p * 32 + d];
    red[tid] = acc;
    __syncthreads();
    if (tid < 32) {
        float s = 0.f;
        #pragma unroll
        for (int i = 0; i < 8; ++i) s += red[i * 32 + tid];
        agg_s[tid] = s;
    }
    __syncthreads();
    if (tid < 32) {
        float acc2 = bu[d];
        if (FIRST) {
            #pragma unroll
            for (int k = 0; k < 32; ++k) acc2 = fmaf(agg_s[k], Wu[k * 32 + d], acc2);
        } else {
            #pragma unroll
            for (int k = 0; k < 32; ++k) acc2 = fmaf(x_prev[a * 32 + k], Wu[k * 32 + d], acc2);
            #pragma unroll
            for (int k = 0; k < 32; ++k) acc2 = fmaf(agg_s[k], Wu[(32 + k) * 32 + d], acc2);
        }
        float xn = fmaxf(acc2, 0.f);
        xnew_s[d] = xn;
        x_new[a * 32 + d] = xn;
    }
    __syncthreads();
    if (!LAST) {
        if (tid < 32) {
            float acc3 = bm_next[d];
            #pragma unroll
            for (int k = 0; k < 32; ++k) acc3 = fmaf(xnew_s[k], Wm_next[k * 32 + d], acc3);
            Pau_next[a * 32 + d] = acc3;
        }
    }
    if (tid == 0) {
        float q0 = beA[0], q1 = beA[1], t0 = beB[0], t1 = beB[1];
        #pragma unroll
        for (int k = 0; k < 32; ++k) {
            q0 = fmaf(xnew_s[k], WeA[k * 2],     q0);
            q1 = fmaf(xnew_s[k], WeA[k * 2 + 1], q1);
            t0 = fmaf(xnew_s[k], WeB[k * 2],     t0);
            t1 = fmaf(xnew_s[k], WeB[k * 2 + 1], t1);
        }
        RapA[a] = make_float2(q0, q1);
        RapB[a] = make_float2(t0, t1);
    }
}

// ---------------------------------------------------------------------------
extern "C" void kernel_launch(void* const* d_in, const int* in_sizes, int n_in,
                              void* d_out_v, int out_size, void* d_ws, size_t ws_size,
                              hipStream_t stream)
{
    const float*  x_ue   = (const float*)d_in[0];
    const float2* e0ua   = (const float2*)d_in[1];
    const float2* e0au   = (const float2*)d_in[2];
    const int*    src    = (const int*)d_in[3];
    const int*    dst    = (const int*)d_in[4];
    const float* Wm1_ua = (const float*)d_in[5];
    const float* bm1_ua = (const float*)d_in[6];
    const float* Wm1_au = (const float*)d_in[7];
    const float* bm1_au = (const float*)d_in[8];
    const float* Wu1_ap = (const float*)d_in[9];
    const float* bu1_ap = (const float*)d_in[10];
    const float* Wu1_ue = (const float*)d_in[11];
    const float* bu1_ue = (const float*)d_in[12];
    const float* We1_ua = (const float*)d_in[13];
    const float* be1_ua = (const float*)d_in[14];
    const float* We1_au = (const float*)d_in[15];
    const float* be1_au = (const float*)d_in[16];
    const float* Wm_ua  = (const float*)d_in[17];
    const float* bm_ua  = (const float*)d_in[18];
    const float* Wm_au  = (const float*)d_in[19];
    const float* bm_au  = (const float*)d_in[20];
    const float* Wu_ap  = (const float*)d_in[21];
    const float* bu_ap  = (const float*)d_in[22];
    const float* Wu_ue  = (const float*)d_in[23];
    const float* bu_ue  = (const float*)d_in[24];
    const float* We_ua  = (const float*)d_in[25];
    const float* be_ua  = (const float*)d_in[26];
    const float* We_au  = (const float*)d_in[27];
    const float* be_au  = (const float*)d_in[28];
    const float* Wp1    = (const float*)d_in[29];
    const float* bp1    = (const float*)d_in[30];
    const float* Wp2    = (const float*)d_in[31];
    const float* bp2    = (const float*)d_in[32];

    float*  outp    = (float*)d_out_v;
    float2* out_ue  = (float2*)outp;                              // [16384][2]
    float*  out_ap  = outp + N_UE * 2;                            // [128][32]
    float2* out_eua = (float2*)(outp + N_UE * 2 + N_AP * 32);     // [E][2]
    float2* out_eau = (float2*)(outp + N_UE * 2 + N_AP * 32 + (size_t)NE * 2);

    float* ws = (float*)d_ws;
    float* x_ueA  = ws;          ws += N_UE * 32;
    float* x_ueB  = ws;          ws += N_UE * 32;
    float* x_apA  = ws;          ws += N_AP * 32;
    float* x_apB  = ws;          ws += N_AP * 32;
    float* agg_ue = ws;          ws += N_UE * 32;
    float* Qua    = ws;          ws += (N_UE + 1) * 32;
    float* Pau    = ws;          ws += (N_AP + 1) * 32;
    float2* RueA  = (float2*)ws; ws += (N_UE + 2) * 2;
    float2* RueB  = (float2*)ws; ws += (N_UE + 2) * 2;
    float2* RapA  = (float2*)ws; ws += (N_AP + 2) * 2;
    float2* RapB  = (float2*)ws; ws += (N_AP + 2) * 2;
    int* cnt   = (int*)ws;       ws += N_UE;
    int* CU    = (int*)ws;       ws += N_UE + 4;
    int* histD = (int*)ws;       ws += NSB * N_AP;
    int* offsD = (int*)ws;       ws += NSB * N_AP;
    int* CA    = (int*)ws;       ws += N_AP + 4;
    int* cnS   = (int*)ws;       ws += NCHU;
    int* cnD   = (int*)ws;       ws += NCHD_AL;
    int* invS  = (int*)ws;       ws += NE;
    int* invD  = (int*)ws;       ws += NE;
    int* dtS   = (int*)ws;       ws += NEP;
    int* srcD  = (int*)ws;       ws += NEPD;
    float2* attS = (float2*)ws;  ws += (size_t)NEP * 2;
    float2* attD = (float2*)ws;  ws += (size_t)NEPD * 2;
    float* partialU = ws;        ws += (size_t)NCHU * 32;         // 35.6 MB
    float* partialA = ws;        ws += (size_t)NCHD_AL * 32;      // 16.8 MB
    unsigned short* histS = (unsigned short*)partialU;            // 8 MB alias
    unsigned short* baseS = (unsigned short*)(partialU + (size_t)(NSB * N_UE / 2)); // 8 MB alias

    dim3 blk(256);

    // ---- prefill sentinels + sort structure ----
    prefill<<<NEP / 256, blk, 0, stream>>>(dtS, srcD, cnS, cnD);
    hist_both<<<NSB, blk, 0, stream>>>(src, dst, histS, histD);
    colscan_kernel<<<N_UE / 256, blk, 0, stream>>>(histS, baseS, cnt);
    scan_src<<<1, blk, 0, stream>>>(cnt, CU);
    scan_dst<<<1, dim3(128), 0, stream>>>(histD, offsD, CA);
    scatter_both<<<NSB, blk, 0, stream>>>(src, dst, e0ua, e0au, baseS, CU, offsD,
                                          dtS, attS, invS, srcD, attD, invD);
    build_map_src<<<N_UE / 256, blk, 0, stream>>>(CU, cnS);
    build_map_dst<<<1, dim3(128), 0, stream>>>(CA, cnD);

    init_kernel<<<N_UE * 32 / 256, blk, 0, stream>>>(x_ue, Wm1_ua, bm1_ua, bm1_au, Qua, Pau);

    const int PB = SRC_BLKS + DST_BLKS;

    // ---- layer 1 ----
    pass_both<false><<<PB, blk, 0, stream>>>(
        cnS, dtS, attS, cnD, srcD, attD,
        nullptr, nullptr, nullptr, nullptr, nullptr, nullptr,
        Qua, Pau, Wm1_ua + 32, Wm1_au, partialU, partialA);
    reduce_ue<<<N_UE * 32 / 256, blk, 0, stream>>>(CU, partialU, agg_ue);
    node_ue_kernel<true, false><<<N_UE / 64, dim3(64), 0, stream>>>(
        x_ue, agg_ue, Wu1_ue, bu1_ue, Wm_ua, bm_ua, We1_ua, We1_au,
        nullptr, nullptr, nullptr, nullptr,
        x_ueA, Qua, RueA, RueB, nullptr);
    node_ap_kernel<true, false><<<N_AP, blk, 0, stream>>>(
        partialA, CA, nullptr, Wu1_ap, bu1_ap, Wm_au, bm_au,
        We1_ua + 64, be1_ua, We1_au + 64, be1_au,
        x_apA, Pau, RapA, RapB);

    // ---- layer 2 (edge-update 1 fused) ----
    pass_both<true><<<PB, blk, 0, stream>>>(
        cnS, dtS, attS, cnD, srcD, attD,
        RueA, RueB, RapA, RapB, We1_ua + 128, We1_au + 128,
        Qua, Pau, Wm_ua + 1024, Wm_au + 1024, partialU, partialA);
    reduce_ue<<<N_UE * 32 / 256, blk, 0, stream>>>(CU, partialU, agg_ue);
    node_ue_kernel<false, false><<<N_UE / 64, dim3(64), 0, stream>>>(
        x_ueA, agg_ue, Wu_ue, bu_ue, Wm_ua + 1088, bm_ua + 32, We_ua, We_au,
        nullptr, nullptr, nullptr, nullptr,
        x_ueB, Qua, RueA, RueB, nullptr);
    node_ap_kernel<false, false><<<N_AP, blk, 0, stream>>>(
        partialA, CA, x_apA, Wu_ap, bu_ap, Wm_au + 1088, bm_au + 32,
        We_ua + 64, be_ua, We_au + 64, be_au,
        x_apB, Pau, RapA, RapB);

    // ---- layer 3 (edge-update 2 fused) ----
    pass_both<true><<<PB, blk, 0, stream>>>(
        cnS, dtS, attS, cnD, srcD, attD,
        RueA, RueB, RapA, RapB, We_ua + 128, We_au + 128,
        Qua, Pau, Wm_ua + 2112, Wm_au + 2112, partialU, partialA);
    reduce_ue<<<N_UE * 32 / 256, blk, 0, stream>>>(CU, partialU, agg_ue);
    node_ue_kernel<false, false><<<N_UE / 64, dim3(64), 0, stream>>>(
        x_ueB, agg_ue, Wu_ue + 2048, bu_ue + 32, Wm_ua + 2176, bm_ua + 64,
        We_ua + 132, We_au + 132,
        nullptr, nullptr, nullptr, nullptr,
        x_ueA, Qua, RueA, RueB, nullptr);
    node_ap_kernel<false, false><<<N_AP, blk, 0, stream>>>(
        partialA, CA, x_apB, Wu_ap + 2048, bu_ap + 32, Wm_au + 2176, bm_au + 64,
        We_ua + 196, be_ua + 2, We_au + 196, be_au + 2,
        x_apA, Pau, RapA, RapB);

    // ---- layer 4 (edge-update 3 fused) ----
    pass_both<true><<<PB, blk, 0, stream>>>(
        cnS, dtS, attS, cnD, srcD, attD,
        RueA, RueB, RapA, RapB, We_ua + 260, We_au + 260,
        Qua, Pau, Wm_ua + 3200, Wm_au + 3200, partialU, partialA);
    reduce_ue<<<N_UE * 32 / 256, blk, 0, stream>>>(CU, partialU, agg_ue);
    node_ue_kernel<false, true><<<N_UE / 64, dim3(64), 0, stream>>>(
        x_ueA, agg_ue, Wu_ue + 4096, bu_ue + 64, nullptr, nullptr,
        We_ua + 264, We_au + 264,
        Wp1, bp1, Wp2, bp2,
        x_ueB, nullptr, RueA, RueB, out_ue);
    node_ap_kernel<false, true><<<N_AP, blk, 0, stream>>>(
        partialA, CA, x_apA, Wu_ap + 4096, bu_ap + 64, nullptr, nullptr,
        We_ua + 328, be_ua + 4, We_au + 328, be_au + 4,
        out_ap, nullptr, RapA, RapB);

    // ---- final edge update (layer 4), original order ----
    final_edge<<<NE / 256, blk, 0, stream>>>(
        src, dst, invS, invD, attS, attD,
        RueA, RueB, RapA, RapB,
        We_ua + 392, We_au + 392, out_eua, out_eau);
}